// Round 1
// baseline (3394.108 us; speedup 1.0000x reference)
//
#include <hip/hip_runtime.h>
#include <cstdint>

#define BB   4096
#define TT   7
#define INF  512
#define HH   1024
#define OUTF 512
#define G3   3072   // 3*H

typedef short bf16x8 __attribute__((ext_vector_type(8)));
typedef float f32x4  __attribute__((ext_vector_type(4)));
typedef int   i32x4  __attribute__((ext_vector_type(4)));

static __device__ __forceinline__ unsigned short f2bf(float f) {
  unsigned u = __float_as_uint(f);
  unsigned r = ((u >> 16) & 1u) + 0x7FFFu;   // RNE
  return (unsigned short)((u + r) >> 16);
}

__global__ __launch_bounds__(256)
void cvt_f32_to_bf16_x4(const float* __restrict__ in, unsigned short* __restrict__ out, int n4) {
  int i = blockIdx.x * 256 + threadIdx.x;
  if (i >= n4) return;
  const float4 v = ((const float4*)in)[i];
  ushort4 o;
  o.x = f2bf(v.x); o.y = f2bf(v.y); o.z = f2bf(v.z); o.w = f2bf(v.w);
  ((ushort4*)out)[i] = o;
}

// C[M,N] = A[M,K] @ W[N,K]^T + bias[N], A/W bf16 (row-major, K contiguous), C f32.
// 128x128 tile, BK=32, 4 waves of 64x64 (4x4 16x16 fragments each).
__global__ __launch_bounds__(256)
void gemm_nt_bias(const unsigned short* __restrict__ A, int lda,
                  const unsigned short* __restrict__ W, int K,
                  const float* __restrict__ bias,
                  float* __restrict__ C, int ldc) {
  __shared__ __attribute__((aligned(16))) unsigned short As[128][40];
  __shared__ __attribute__((aligned(16))) unsigned short Ws[128][40];
  const int tid  = threadIdx.x;
  const int lane = tid & 63;
  const int wid  = tid >> 6;
  const long bm = (long)blockIdx.x * 128;
  const long bn = (long)blockIdx.y * 128;
  const int wr = (wid >> 1) * 64;
  const int wc = (wid & 1) * 64;
  const int sr = tid >> 2;          // staging row 0..63
  const int sc = (tid & 3) * 8;     // staging col chunk (elements)
  const int fr = lane & 15;         // fragment row/col within 16
  const int fk = (lane >> 4) * 8;   // fragment k offset (8 contiguous bf16)

  f32x4 acc[4][4] = {};

  for (int kt = 0; kt < K; kt += 32) {
    __syncthreads();
    *(i32x4*)&As[sr][sc]      = *(const i32x4*)&A[(bm + sr) * (long)lda + kt + sc];
    *(i32x4*)&As[sr + 64][sc] = *(const i32x4*)&A[(bm + sr + 64) * (long)lda + kt + sc];
    *(i32x4*)&Ws[sr][sc]      = *(const i32x4*)&W[(bn + sr) * (long)K + kt + sc];
    *(i32x4*)&Ws[sr + 64][sc] = *(const i32x4*)&W[(bn + sr + 64) * (long)K + kt + sc];
    __syncthreads();
    bf16x8 af[4], wf[4];
#pragma unroll
    for (int i = 0; i < 4; ++i) {
      af[i] = *(const bf16x8*)&As[wr + i * 16 + fr][fk];
      wf[i] = *(const bf16x8*)&Ws[wc + i * 16 + fr][fk];
    }
#pragma unroll
    for (int mi = 0; mi < 4; ++mi)
#pragma unroll
      for (int ni = 0; ni < 4; ++ni)
        acc[mi][ni] = __builtin_amdgcn_mfma_f32_16x16x32_bf16(af[mi], wf[ni], acc[mi][ni], 0, 0, 0);
  }

  const int q = lane >> 4;
#pragma unroll
  for (int ni = 0; ni < 4; ++ni) {
    const long col = bn + wc + ni * 16 + fr;
    const float bv = bias[col];
#pragma unroll
    for (int mi = 0; mi < 4; ++mi) {
      const long row = bm + wr + mi * 16 + q * 4;
#pragma unroll
      for (int j = 0; j < 4; ++j)
        C[(row + j) * (long)ldc + col] = acc[mi][ni][j] + bv;
    }
  }
}

// h_new = (1-z)*n + z*h_old per element; writes f32 + bf16 copies; optional aux += mean(h^2)
__global__ __launch_bounds__(256)
void gru_gate(const float* __restrict__ gi, const float* __restrict__ gh,
              float* __restrict__ hf, unsigned short* __restrict__ hb,
              float* __restrict__ aux) {
  const int idx = blockIdx.x * 256 + threadIdx.x;   // over B*H
  const int b = idx >> 10;                          // H = 1024
  const int c = idx & 1023;
  const long base = (long)b * G3 + c;
  const float ir = gi[base], iz = gi[base + HH], inn = gi[base + 2 * HH];
  const float hr = gh[base], hz = gh[base + HH], hn = gh[base + 2 * HH];
  const float r = 1.f / (1.f + __expf(-(ir + hr)));
  const float z = 1.f / (1.f + __expf(-(iz + hz)));
  const float n = tanhf(inn + r * hn);
  const float h = (1.f - z) * n + z * hf[idx];
  hf[idx] = h;
  hb[idx] = f2bf(h);
  if (aux != nullptr) {
    float v = h * h;
#pragma unroll
    for (int off = 32; off > 0; off >>= 1) v += __shfl_down(v, off);
    __shared__ float wsum[4];
    const int lane = threadIdx.x & 63, w = threadIdx.x >> 6;
    if (lane == 0) wsum[w] = v;
    __syncthreads();
    if (threadIdx.x == 0)
      atomicAdd(aux, (wsum[0] + wsum[1] + wsum[2] + wsum[3]) * (1.f / ((float)BB * (float)HH)));
  }
}

__global__ __launch_bounds__(256)
void combine_out(const float* __restrict__ o1, const float* __restrict__ o2,
                 float* __restrict__ out) {  // out = d_out + t*OUTF, row stride T*OUT
  const int idx = blockIdx.x * 256 + threadIdx.x;  // over B*OUT
  const int b = idx >> 9;
  const int c = idx & 511;
  out[(long)b * (TT * OUTF) + c] = tanhf(o1[idx]) + tanhf(o2[idx]);
}

extern "C" void kernel_launch(void* const* d_in, const int* in_sizes, int n_in,
                              void* d_out, int out_size, void* d_ws, size_t ws_size,
                              hipStream_t stream) {
  const float* x    = (const float*)d_in[0];
  const float* Wih1 = (const float*)d_in[1];
  const float* Whh1 = (const float*)d_in[2];
  const float* bih1 = (const float*)d_in[3];
  const float* bhh1 = (const float*)d_in[4];
  const float* Wih2 = (const float*)d_in[5];
  const float* Whh2 = (const float*)d_in[6];
  const float* bih2 = (const float*)d_in[7];
  const float* bhh2 = (const float*)d_in[8];
  const float* Wo1  = (const float*)d_in[9];
  const float* bo1  = (const float*)d_in[10];
  const float* Wo2  = (const float*)d_in[11];
  const float* bo2  = (const float*)d_in[12];

  char* ws = (char*)d_ws;
  size_t off = 0;
  auto alloc = [&](size_t bytes) {
    char* p = ws + off;
    off = (off + bytes + 255) & ~(size_t)255;
    return p;
  };

  unsigned short* xb    = (unsigned short*)alloc((size_t)BB * TT * INF * 2);
  unsigned short* wih1b = (unsigned short*)alloc((size_t)G3 * INF * 2);
  unsigned short* whh1b = (unsigned short*)alloc((size_t)G3 * HH * 2);
  unsigned short* wih2b = (unsigned short*)alloc((size_t)G3 * HH * 2);
  unsigned short* whh2b = (unsigned short*)alloc((size_t)G3 * HH * 2);
  unsigned short* wo1b  = (unsigned short*)alloc((size_t)OUTF * HH * 2);
  unsigned short* wo2b  = (unsigned short*)alloc((size_t)OUTF * HH * 2);
  float* h1f = (float*)alloc((size_t)BB * HH * 4);
  float* h2f = (float*)alloc((size_t)BB * HH * 4);
  unsigned short* h1b = (unsigned short*)alloc((size_t)BB * HH * 2);
  unsigned short* h2b = (unsigned short*)alloc((size_t)BB * HH * 2);
  float* gi = (float*)alloc((size_t)BB * G3 * 4);
  float* gh = (float*)alloc((size_t)BB * G3 * 4);
  float* o1 = gi;                         // reuse gi buffer after gate2 consumed it
  float* o2 = gi + (size_t)BB * OUTF;

  float* aux = (float*)d_out + (size_t)BB * TT * OUTF;

  auto cvt = [&](const float* src, unsigned short* dst, size_t n) {
    int n4 = (int)(n / 4);
    cvt_f32_to_bf16_x4<<<dim3((n4 + 255) / 256), dim3(256), 0, stream>>>(src, dst, n4);
  };
  cvt(x,    xb,    (size_t)BB * TT * INF);
  cvt(Wih1, wih1b, (size_t)G3 * INF);
  cvt(Whh1, whh1b, (size_t)G3 * HH);
  cvt(Wih2, wih2b, (size_t)G3 * HH);
  cvt(Whh2, whh2b, (size_t)G3 * HH);
  cvt(Wo1,  wo1b,  (size_t)OUTF * HH);
  cvt(Wo2,  wo2b,  (size_t)OUTF * HH);

  hipMemsetAsync(h1f, 0, (size_t)BB * HH * 4, stream);
  hipMemsetAsync(h2f, 0, (size_t)BB * HH * 4, stream);
  hipMemsetAsync(h1b, 0, (size_t)BB * HH * 2, stream);
  hipMemsetAsync(h2b, 0, (size_t)BB * HH * 2, stream);
  hipMemsetAsync(aux, 0, 4, stream);

  const dim3 blk(256);
  const dim3 gG(BB / 128, G3 / 128);
  const dim3 gO(BB / 128, OUTF / 128);
  const int gateGrid = BB * HH / 256;
  const int combGrid = BB * OUTF / 256;

  for (int t = 0; t < TT; ++t) {
    // layer 1
    gemm_nt_bias<<<gG, blk, 0, stream>>>(xb + (size_t)t * INF, TT * INF, wih1b, INF, bih1, gi, G3);
    gemm_nt_bias<<<gG, blk, 0, stream>>>(h1b, HH, whh1b, HH, bhh1, gh, G3);
    gru_gate<<<gateGrid, blk, 0, stream>>>(gi, gh, h1f, h1b, nullptr);
    // layer 2
    gemm_nt_bias<<<gG, blk, 0, stream>>>(h1b, HH, wih2b, HH, bih2, gi, G3);
    gemm_nt_bias<<<gG, blk, 0, stream>>>(h2b, HH, whh2b, HH, bhh2, gh, G3);
    gru_gate<<<gateGrid, blk, 0, stream>>>(gi, gh, h2f, h2b, aux);
    // output head
    gemm_nt_bias<<<gO, blk, 0, stream>>>(h1b, HH, wo1b, HH, bo1, o1, OUTF);
    gemm_nt_bias<<<gO, blk, 0, stream>>>(h2b, HH, wo2b, HH, bo2, o2, OUTF);
    combine_out<<<combGrid, blk, 0, stream>>>(o1, o2, (float*)d_out + (size_t)t * OUTF);
  }
}

// Round 2
// 2032.879 us; speedup vs baseline: 1.6696x; 1.6696x over previous
//
#include <hip/hip_runtime.h>
#include <cstdint>

#define BB   4096
#define TT   7
#define INF  512
#define HH   1024
#define OUTF 512
#define G3   3072   // 3*H

typedef short bf16x8 __attribute__((ext_vector_type(8)));
typedef float f32x4  __attribute__((ext_vector_type(4)));

static __device__ __forceinline__ unsigned short f2bf(float f) {
  unsigned u = __float_as_uint(f);
  unsigned r = ((u >> 16) & 1u) + 0x7FFFu;   // RNE
  return (unsigned short)((u + r) >> 16);
}

#define GLDS16(gp, lp)                                                        \
  __builtin_amdgcn_global_load_lds(                                           \
      (const __attribute__((address_space(1))) void*)(gp),                    \
      (__attribute__((address_space(3))) void*)(lp), 16, 0, 0)

__global__ __launch_bounds__(256)
void cvt_f32_to_bf16_x4(const float* __restrict__ in, unsigned short* __restrict__ out, int n4) {
  int i = blockIdx.x * 256 + threadIdx.x;
  if (i >= n4) return;
  const float4 v = ((const float4*)in)[i];
  ushort4 o;
  o.x = f2bf(v.x); o.y = f2bf(v.y); o.z = f2bf(v.z); o.w = f2bf(v.w);
  ((ushort4*)out)[i] = o;
}

// C[M,N] = A[M,K] @ W[N,K]^T + bias[N], A/W bf16 row-major (K contiguous), C f32.
// 128x128 tile, BK=32, 4 waves of 64x64 (4x4 16x16x32 fragments each).
// m97 structure: global_load_lds width=16 into linear [128][32] LDS, 2 barriers/K-step.
__global__ __launch_bounds__(256)
void gemm_nt_bias(const unsigned short* __restrict__ A, int lda,
                  const unsigned short* __restrict__ W, int K,
                  const float* __restrict__ bias,
                  float* __restrict__ C, int ldc) {
  __shared__ __attribute__((aligned(16))) unsigned short As[128 * 32];
  __shared__ __attribute__((aligned(16))) unsigned short Ws[128 * 32];
  const int tid  = threadIdx.x;
  const int lane = tid & 63;
  const int wid  = tid >> 6;
  const long bm = (long)blockIdx.x * 128;
  const long bn = (long)blockIdx.y * 128;
  const int wr = (wid >> 1) * 64;
  const int wc = (wid & 1) * 64;
  const int fr = lane & 15;         // fragment row/col within 16
  const int fk = (lane >> 4) * 8;   // fragment k offset (8 contiguous bf16)

  // staging geometry: 16 KB total = 16 wave-chunks of 1024 B (16 rows x 64 B).
  // wave w handles chunks {w, w+4} of As and of Ws; lane loads 16 B.
  const int cc0 = wid, cc1 = wid + 4;
  const int g0 = cc0 * 64 + lane, g1 = cc1 * 64 + lane;
  const int r0 = g0 >> 2, r1 = g1 >> 2;          // row within 128-tile
  const int ce0 = (g0 & 3) * 8, ce1 = (g1 & 3) * 8;  // col offset (elements)
  const unsigned short* a0 = A + (bm + r0) * (long)lda + ce0;
  const unsigned short* a1 = A + (bm + r1) * (long)lda + ce1;
  const unsigned short* w0 = W + (bn + r0) * (long)K + ce0;
  const unsigned short* w1 = W + (bn + r1) * (long)K + ce1;
  __attribute__((address_space(3))) unsigned short* lAs =
      (__attribute__((address_space(3))) unsigned short*)As;
  __attribute__((address_space(3))) unsigned short* lWs =
      (__attribute__((address_space(3))) unsigned short*)Ws;

  f32x4 acc[4][4] = {};

  for (int kt = 0; kt < K; kt += 32) {
    __syncthreads();   // previous iteration's reads done before overwrite
    GLDS16(a0 + kt, lAs + cc0 * 512);
    GLDS16(a1 + kt, lAs + cc1 * 512);
    GLDS16(w0 + kt, lWs + cc0 * 512);
    GLDS16(w1 + kt, lWs + cc1 * 512);
    __syncthreads();   // compiler drains vmcnt before s_barrier -> data ready
    bf16x8 af[4], wf[4];
#pragma unroll
    for (int i = 0; i < 4; ++i) {
      af[i] = *(const bf16x8*)&As[(wr + i * 16 + fr) * 32 + fk];
      wf[i] = *(const bf16x8*)&Ws[(wc + i * 16 + fr) * 32 + fk];
    }
#pragma unroll
    for (int mi = 0; mi < 4; ++mi)
#pragma unroll
      for (int ni = 0; ni < 4; ++ni)
        acc[mi][ni] = __builtin_amdgcn_mfma_f32_16x16x32_bf16(af[mi], wf[ni], acc[mi][ni], 0, 0, 0);
  }

  const int q = lane >> 4;
#pragma unroll
  for (int ni = 0; ni < 4; ++ni) {
    const long col = bn + wc + ni * 16 + fr;
    const float bv = bias[col];
#pragma unroll
    for (int mi = 0; mi < 4; ++mi) {
      const long row = bm + wr + mi * 16 + q * 4;
#pragma unroll
      for (int j = 0; j < 4; ++j)
        C[(row + j) * (long)ldc + col] = acc[mi][ni][j] + bv;
    }
  }
}

// h_new = (1-z)*n + z*h_old, 4 elements/thread; optional per-block aux partial.
__global__ __launch_bounds__(256)
void gru_gate(const float* __restrict__ gi, const float* __restrict__ gh,
              float* __restrict__ hf, unsigned short* __restrict__ hb,
              float* __restrict__ auxp) {
  const int i4 = blockIdx.x * 256 + threadIdx.x;
  const int e  = i4 << 2;                 // element index, 4 at a time
  const int b = e >> 10;                  // H = 1024
  const int c = e & 1023;
  const long base = (long)b * G3 + c;
  const f32x4 ir  = *(const f32x4*)(gi + base);
  const f32x4 iz  = *(const f32x4*)(gi + base + HH);
  const f32x4 inn = *(const f32x4*)(gi + base + 2 * HH);
  const f32x4 hr  = *(const f32x4*)(gh + base);
  const f32x4 hz  = *(const f32x4*)(gh + base + HH);
  const f32x4 hn  = *(const f32x4*)(gh + base + 2 * HH);
  const f32x4 h   = *(const f32x4*)(hf + e);
  f32x4 hnew;
  float vsum = 0.f;
#pragma unroll
  for (int j = 0; j < 4; ++j) {
    const float r = 1.f / (1.f + __expf(-(ir[j] + hr[j])));
    const float z = 1.f / (1.f + __expf(-(iz[j] + hz[j])));
    const float n = tanhf(inn[j] + r * hn[j]);
    hnew[j] = (1.f - z) * n + z * h[j];
    vsum += hnew[j] * hnew[j];
  }
  *(f32x4*)(hf + e) = hnew;
  ushort4 o;
  o.x = f2bf(hnew[0]); o.y = f2bf(hnew[1]); o.z = f2bf(hnew[2]); o.w = f2bf(hnew[3]);
  *(ushort4*)(hb + e) = o;
  if (auxp != nullptr) {
#pragma unroll
    for (int off = 32; off > 0; off >>= 1) vsum += __shfl_down(vsum, off);
    __shared__ float wsum[4];
    if ((threadIdx.x & 63) == 0) wsum[threadIdx.x >> 6] = vsum;
    __syncthreads();
    if (threadIdx.x == 0)
      auxp[blockIdx.x] = wsum[0] + wsum[1] + wsum[2] + wsum[3];
  }
}

// deterministic single-block reduce of all aux partials -> aux scalar
__global__ __launch_bounds__(256)
void aux_reduce(const float* __restrict__ p, int n, float* __restrict__ out, float scale) {
  float s = 0.f;
  for (int i = threadIdx.x; i < n; i += 256) s += p[i];
#pragma unroll
  for (int off = 32; off > 0; off >>= 1) s += __shfl_down(s, off);
  __shared__ float wsum[4];
  if ((threadIdx.x & 63) == 0) wsum[threadIdx.x >> 6] = s;
  __syncthreads();
  if (threadIdx.x == 0) out[0] = (wsum[0] + wsum[1] + wsum[2] + wsum[3]) * scale;
}

__global__ __launch_bounds__(256)
void combine_out(const float* __restrict__ o1, const float* __restrict__ o2,
                 float* __restrict__ out) {  // out = d_out + t*OUTF, row stride T*OUT
  const int i4 = blockIdx.x * 256 + threadIdx.x;
  const int e  = i4 << 2;                 // over B*OUT
  const int b = e >> 9;
  const int c = e & 511;
  const f32x4 a = *(const f32x4*)(o1 + e);
  const f32x4 bb = *(const f32x4*)(o2 + e);
  f32x4 r;
#pragma unroll
  for (int j = 0; j < 4; ++j) r[j] = tanhf(a[j]) + tanhf(bb[j]);
  *(f32x4*)(out + (long)b * (TT * OUTF) + c) = r;
}

extern "C" void kernel_launch(void* const* d_in, const int* in_sizes, int n_in,
                              void* d_out, int out_size, void* d_ws, size_t ws_size,
                              hipStream_t stream) {
  const float* x    = (const float*)d_in[0];
  const float* Wih1 = (const float*)d_in[1];
  const float* Whh1 = (const float*)d_in[2];
  const float* bih1 = (const float*)d_in[3];
  const float* bhh1 = (const float*)d_in[4];
  const float* Wih2 = (const float*)d_in[5];
  const float* Whh2 = (const float*)d_in[6];
  const float* bih2 = (const float*)d_in[7];
  const float* bhh2 = (const float*)d_in[8];
  const float* Wo1  = (const float*)d_in[9];
  const float* bo1  = (const float*)d_in[10];
  const float* Wo2  = (const float*)d_in[11];
  const float* bo2  = (const float*)d_in[12];

  char* ws = (char*)d_ws;
  size_t off = 0;
  auto alloc = [&](size_t bytes) {
    char* p = ws + off;
    off = (off + bytes + 255) & ~(size_t)255;
    return p;
  };

  unsigned short* xb    = (unsigned short*)alloc((size_t)BB * TT * INF * 2);
  unsigned short* wih1b = (unsigned short*)alloc((size_t)G3 * INF * 2);
  unsigned short* whh1b = (unsigned short*)alloc((size_t)G3 * HH * 2);
  unsigned short* wih2b = (unsigned short*)alloc((size_t)G3 * HH * 2);
  unsigned short* whh2b = (unsigned short*)alloc((size_t)G3 * HH * 2);
  unsigned short* wo1b  = (unsigned short*)alloc((size_t)OUTF * HH * 2);
  unsigned short* wo2b  = (unsigned short*)alloc((size_t)OUTF * HH * 2);
  float* h1f = (float*)alloc((size_t)BB * HH * 4);
  float* h2f = (float*)alloc((size_t)BB * HH * 4);
  unsigned short* h1b = (unsigned short*)alloc((size_t)BB * HH * 2);
  unsigned short* h2b = (unsigned short*)alloc((size_t)BB * HH * 2);
  float* gi = (float*)alloc((size_t)BB * G3 * 4);
  float* gh = (float*)alloc((size_t)BB * G3 * 4);
  float* auxp = (float*)alloc((size_t)TT * (BB * HH / 1024) * 4);
  float* o1 = gi;                         // reuse gi buffer after gate2 consumed it
  float* o2 = gi + (size_t)BB * OUTF;

  float* aux = (float*)d_out + (size_t)BB * TT * OUTF;

  auto cvt = [&](const float* src, unsigned short* dst, size_t n) {
    int n4 = (int)(n / 4);
    cvt_f32_to_bf16_x4<<<dim3((n4 + 255) / 256), dim3(256), 0, stream>>>(src, dst, n4);
  };
  cvt(x,    xb,    (size_t)BB * TT * INF);
  cvt(Wih1, wih1b, (size_t)G3 * INF);
  cvt(Whh1, whh1b, (size_t)G3 * HH);
  cvt(Wih2, wih2b, (size_t)G3 * HH);
  cvt(Whh2, whh2b, (size_t)G3 * HH);
  cvt(Wo1,  wo1b,  (size_t)OUTF * HH);
  cvt(Wo2,  wo2b,  (size_t)OUTF * HH);

  hipMemsetAsync(h1f, 0, (size_t)BB * HH * 4, stream);
  hipMemsetAsync(h2f, 0, (size_t)BB * HH * 4, stream);
  hipMemsetAsync(h1b, 0, (size_t)BB * HH * 2, stream);
  hipMemsetAsync(h2b, 0, (size_t)BB * HH * 2, stream);

  const dim3 blk(256);
  const dim3 gG(BB / 128, G3 / 128);
  const dim3 gO(BB / 128, OUTF / 128);
  const int gateGrid = BB * HH / 1024;    // 4096 blocks, 4 elem/thread
  const int combGrid = BB * OUTF / 1024;  // 2048 blocks

  for (int t = 0; t < TT; ++t) {
    // layer 1
    gemm_nt_bias<<<gG, blk, 0, stream>>>(xb + (size_t)t * INF, TT * INF, wih1b, INF, bih1, gi, G3);
    gemm_nt_bias<<<gG, blk, 0, stream>>>(h1b, HH, whh1b, HH, bhh1, gh, G3);
    gru_gate<<<gateGrid, blk, 0, stream>>>(gi, gh, h1f, h1b, nullptr);
    // layer 2
    gemm_nt_bias<<<gG, blk, 0, stream>>>(h1b, HH, wih2b, HH, bih2, gi, G3);
    gemm_nt_bias<<<gG, blk, 0, stream>>>(h2b, HH, whh2b, HH, bhh2, gh, G3);
    gru_gate<<<gateGrid, blk, 0, stream>>>(gi, gh, h2f, h2b, auxp + (size_t)t * gateGrid);
    // output head
    gemm_nt_bias<<<gO, blk, 0, stream>>>(h1b, HH, wo1b, HH, bo1, o1, OUTF);
    gemm_nt_bias<<<gO, blk, 0, stream>>>(h2b, HH, wo2b, HH, bo2, o2, OUTF);
    combine_out<<<combGrid, blk, 0, stream>>>(o1, o2, (float*)d_out + (size_t)t * OUTF);
  }
  aux_reduce<<<1, blk, 0, stream>>>(auxp, TT * gateGrid, aux, 1.f / ((float)BB * (float)HH));
}

// Round 4
// 1568.467 us; speedup vs baseline: 2.1640x; 1.2961x over previous
//
#include <hip/hip_runtime.h>
#include <cstdint>

#define BB   4096
#define TT   7
#define INF  512
#define HH   1024
#define OUTF 512
#define G3   3072   // 3*H

typedef short bf16x8 __attribute__((ext_vector_type(8)));
typedef float f32x4  __attribute__((ext_vector_type(4)));

static __device__ __forceinline__ unsigned short f2bf(float f) {
  unsigned u = __float_as_uint(f);
  unsigned r = ((u >> 16) & 1u) + 0x7FFFu;   // RNE
  return (unsigned short)((u + r) >> 16);
}
static __device__ __forceinline__ float bf2f(unsigned short s) {
  return __uint_as_float(((unsigned)s) << 16);
}

#define GLDS16(gp, lp)                                                        \
  __builtin_amdgcn_global_load_lds(                                           \
      (const __attribute__((address_space(1))) void*)(gp),                    \
      (__attribute__((address_space(3))) void*)(lp), 16, 0, 0)

__device__ __forceinline__ int xcd_swz(int bid, int nwg) {
  return (bid & 7) * (nwg >> 3) + (bid >> 3);   // bijective: nwg % 8 == 0
}

__global__ __launch_bounds__(256)
void cvt_f32_to_bf16_x4(const float* __restrict__ in, unsigned short* __restrict__ out, int n4) {
  int i = blockIdx.x * 256 + threadIdx.x;
  if (i >= n4) return;
  const float4 v = ((const float4*)in)[i];
  ushort4 o;
  o.x = f2bf(v.x); o.y = f2bf(v.y); o.z = f2bf(v.z); o.w = f2bf(v.w);
  ((ushort4*)out)[i] = o;
}

// ---------------------------------------------------------------------------
// GEMM core: C[M,N] = A[M,K] @ W[N,K]^T + bias. bf16 in, f32 acc.
// 2-phase double-buffered: STAGE(next) issued BEFORE ds_read+MFMA of current;
// one barrier per K-iter (compiler drains vmcnt before s_barrier).
// mode: 0 = f32 store; 1 = f32 tanh; 2 = f32 tanh + add[]; 3 = bf16 store.
// NOTE: exactly ONE gemm_core call per kernel (single 32KB __shared__).
// ---------------------------------------------------------------------------
template<int BM, int BN, int WM, int WN, int GN>
__device__ __forceinline__ void gemm_core(
    const unsigned short* __restrict__ A, long lda, long bm,
    const unsigned short* __restrict__ Wp, long ldw, int K,
    const float* __restrict__ biasp,
    void* __restrict__ Cp, long ldc,
    const float* __restrict__ addp, long ldadd, int mode)
{
  constexpr int ABUF = BM * 32;              // ushorts per A buffer
  constexpr int WBUF = BN * 32;
  constexpr int AR = (BM * 4) / 256;
  constexpr int WR = (BN * 4) / 256;
  __shared__ __attribute__((aligned(16))) unsigned short sm[2 * (ABUF + WBUF)];
  unsigned short* As = sm;
  unsigned short* Ws = sm + 2 * ABUF;
  __attribute__((address_space(3))) unsigned short* lAs =
      (__attribute__((address_space(3))) unsigned short*)As;
  __attribute__((address_space(3))) unsigned short* lWs =
      (__attribute__((address_space(3))) unsigned short*)Ws;

  const int tid  = threadIdx.x;
  const int lane = tid & 63;
  const int wid  = tid >> 6;
  const int wr = (wid / GN) * (WM * 16);
  const int wc = (wid % GN) * (WN * 16);
  const int fr = lane & 15;
  const int fk = (lane >> 4) * 8;

  const unsigned short* gpa[AR];
  const unsigned short* gpw[WR];
  int lofa[AR], lofw[WR];
#pragma unroll
  for (int r = 0; r < AR; ++r) {
    const int c = r * 256 + tid;
    gpa[r] = A + (bm + (c >> 2)) * lda + (c & 3) * 8;
    lofa[r] = c * 8;
  }
#pragma unroll
  for (int r = 0; r < WR; ++r) {
    const int c = r * 256 + tid;
    gpw[r] = Wp + (long)(c >> 2) * ldw + (c & 3) * 8;
    lofw[r] = c * 8;
  }

#define STAGE(buf, kt) do {                                                   \
    _Pragma("unroll")                                                         \
    for (int r = 0; r < AR; ++r) GLDS16(gpa[r] + (kt), lAs + (buf) * ABUF + lofa[r]); \
    _Pragma("unroll")                                                         \
    for (int r = 0; r < WR; ++r) GLDS16(gpw[r] + (kt), lWs + (buf) * WBUF + lofw[r]); \
  } while (0)

  f32x4 acc[WM][WN] = {};
  STAGE(0, 0);
  __syncthreads();
  const int NK = K >> 5;
  for (int it = 0; it < NK; ++it) {
    const int cur = it & 1;
    if (it + 1 < NK) STAGE(cur ^ 1, (it + 1) << 5);   // prefetch next tile
    bf16x8 af[WM], wf[WN];
#pragma unroll
    for (int i = 0; i < WM; ++i)
      af[i] = *(const bf16x8*)&As[cur * ABUF + (wr + i * 16 + fr) * 32 + fk];
#pragma unroll
    for (int i = 0; i < WN; ++i)
      wf[i] = *(const bf16x8*)&Ws[cur * WBUF + (wc + i * 16 + fr) * 32 + fk];
#pragma unroll
    for (int mi = 0; mi < WM; ++mi)
#pragma unroll
      for (int ni = 0; ni < WN; ++ni)
        acc[mi][ni] = __builtin_amdgcn_mfma_f32_16x16x32_bf16(af[mi], wf[ni], acc[mi][ni], 0, 0, 0);
    __syncthreads();
  }
#undef STAGE

  const int q = lane >> 4;
#pragma unroll
  for (int ni = 0; ni < WN; ++ni) {
    const int col = wc + ni * 16 + fr;
    const float bv = biasp[col];
#pragma unroll
    for (int mi = 0; mi < WM; ++mi) {
      const long row = bm + wr + mi * 16 + q * 4;
#pragma unroll
      for (int j = 0; j < 4; ++j) {
        const float v = acc[mi][ni][j] + bv;
        if (mode == 0)      ((float*)Cp)[(row + j) * ldc + col] = v;
        else if (mode == 1) ((float*)Cp)[(row + j) * ldc + col] = tanhf(v);
        else if (mode == 2) ((float*)Cp)[(row + j) * ldc + col] = tanhf(v) + addp[(row + j) * ldadd + col];
        else                ((unsigned short*)Cp)[(row + j) * ldc + col] = f2bf(v);
      }
    }
  }
}

// gi1 (bf16 out). Hoisted: A=[B*T,512], gx=224. Per-step: gx=32, lda=T*INF.
__global__ __launch_bounds__(256)
void k_gi1(const unsigned short* __restrict__ A, long lda,
           const unsigned short* __restrict__ W, const float* __restrict__ bias,
           unsigned short* __restrict__ C, int gx)
{
  const int wg = xcd_swz(blockIdx.x, gridDim.x);
  const int bx = wg % gx, by = wg / gx;
  gemm_core<128,128,4,4,2>(A, lda, (long)bx * 128, W + (long)by * 128 * INF, INF, INF,
                           bias + by * 128, C + by * 128, G3, nullptr, 0, 3);
}

// gh1 = h1 @ Whh1^T and gh2 = h2 @ Whh2^T in one 1536-block dispatch
__global__ __launch_bounds__(256)
void k_gh_dual(const unsigned short* __restrict__ h1b, const unsigned short* __restrict__ h2b,
               const unsigned short* __restrict__ W1, const unsigned short* __restrict__ W2,
               const float* __restrict__ b1, const float* __restrict__ b2,
               float* __restrict__ gh1, float* __restrict__ gh2)
{
  const int wg = xcd_swz(blockIdx.x, gridDim.x);   // 1536
  const int bx = wg % 32;
  const int by = (wg / 32) % 24;
  const int z  = wg / (32 * 24);
  const unsigned short* Aa = z ? h2b : h1b;
  const unsigned short* Ww = (z ? W2 : W1) + (long)by * 128 * HH;
  const float* bias = (z ? b2 : b1) + by * 128;
  float* C = (z ? gh2 : gh1) + by * 128;
  gemm_core<128,128,4,4,2>(Aa, HH, (long)bx * 128, Ww, HH, HH, bias, C, G3, nullptr, 0, 0);
}

// gi2 = h1 @ Wih2^T (f32) and o1t = tanh(h1 @ Wo1^T + bo1), single call site
__global__ __launch_bounds__(256)
void k_gi2_o1(const unsigned short* __restrict__ h1b,
              const unsigned short* __restrict__ Wih2, const float* __restrict__ bih2,
              float* __restrict__ gi2,
              const unsigned short* __restrict__ Wo1, const float* __restrict__ bo1,
              float* __restrict__ o1t)
{
  const int wg = xcd_swz(blockIdx.x, gridDim.x);   // 896
  const int bx = wg % 32;
  const int by = wg / 32;
  const bool g = (by < 24);
  const int bo = by - 24;
  const unsigned short* Ww = g ? (Wih2 + (long)by * 128 * HH) : (Wo1 + (long)bo * 128 * HH);
  const float* bias        = g ? (bih2 + by * 128)            : (bo1 + bo * 128);
  void* C                  = g ? (void*)(gi2 + by * 128)      : (void*)(o1t + bo * 128);
  const long ldc           = g ? (long)G3 : (long)OUTF;
  gemm_core<128,128,4,4,2>(h1b, HH, (long)bx * 128, Ww, HH, HH, bias, C, ldc,
                           nullptr, 0, g ? 0 : 1);
}

// out[b,t,:] = tanh(h2 @ Wo2^T + bo2) + o1t   (64x64 tiles, 512 blocks)
__global__ __launch_bounds__(256)
void k_o2_out(const unsigned short* __restrict__ h2b,
              const unsigned short* __restrict__ Wo2, const float* __restrict__ bo2,
              const float* __restrict__ o1t, float* __restrict__ outp)
{
  const int wg = xcd_swz(blockIdx.x, gridDim.x);   // 512
  const int bx = wg % 64;
  const int by = wg / 64;
  gemm_core<64,64,2,2,2>(h2b, HH, (long)bx * 64, Wo2 + (long)by * 64 * HH, HH, HH,
                         bo2 + by * 64, outp + by * 64, (long)TT * OUTF,
                         o1t + by * 64, OUTF, 2);
}

// GRU gate: h = (1-z)*n + z*h_old, recurrence on bf16 state hb (read+write).
template<bool GIBF>
__global__ __launch_bounds__(256)
void k_gate(const void* __restrict__ gi, long gistride,
            const float* __restrict__ gh,
            unsigned short* __restrict__ hb,
            float* __restrict__ auxp)
{
  const int i4 = blockIdx.x * 256 + threadIdx.x;
  const int e  = i4 << 2;
  const int b = e >> 10;                  // H = 1024
  const int c = e & 1023;
  f32x4 ir, iz, inn;
  if (GIBF) {
    const unsigned short* g = (const unsigned short*)gi + (long)b * gistride + c;
    const ushort4 a0 = *(const ushort4*)(g);
    const ushort4 a1 = *(const ushort4*)(g + HH);
    const ushort4 a2 = *(const ushort4*)(g + 2 * HH);
    ir  = f32x4{bf2f(a0.x), bf2f(a0.y), bf2f(a0.z), bf2f(a0.w)};
    iz  = f32x4{bf2f(a1.x), bf2f(a1.y), bf2f(a1.z), bf2f(a1.w)};
    inn = f32x4{bf2f(a2.x), bf2f(a2.y), bf2f(a2.z), bf2f(a2.w)};
  } else {
    const float* g = (const float*)gi + (long)b * gistride + c;
    ir = *(const f32x4*)g; iz = *(const f32x4*)(g + HH); inn = *(const f32x4*)(g + 2 * HH);
  }
  const float* ghp = gh + (long)b * G3 + c;
  const f32x4 hr = *(const f32x4*)ghp;
  const f32x4 hz = *(const f32x4*)(ghp + HH);
  const f32x4 hn = *(const f32x4*)(ghp + 2 * HH);
  const ushort4 ho = *(const ushort4*)(hb + e);
  const f32x4 h = f32x4{bf2f(ho.x), bf2f(ho.y), bf2f(ho.z), bf2f(ho.w)};
  f32x4 hnew;
  float vsum = 0.f;
#pragma unroll
  for (int j = 0; j < 4; ++j) {
    const float r = 1.f / (1.f + __expf(-(ir[j] + hr[j])));
    const float z = 1.f / (1.f + __expf(-(iz[j] + hz[j])));
    const float n = tanhf(inn[j] + r * hn[j]);
    hnew[j] = (1.f - z) * n + z * h[j];
    vsum += hnew[j] * hnew[j];
  }
  ushort4 o;
  o.x = f2bf(hnew[0]); o.y = f2bf(hnew[1]); o.z = f2bf(hnew[2]); o.w = f2bf(hnew[3]);
  *(ushort4*)(hb + e) = o;
  if (auxp != nullptr) {
#pragma unroll
    for (int off = 32; off > 0; off >>= 1) vsum += __shfl_down(vsum, off);
    __shared__ float wsum[4];
    if ((threadIdx.x & 63) == 0) wsum[threadIdx.x >> 6] = vsum;
    __syncthreads();
    if (threadIdx.x == 0) auxp[blockIdx.x] = wsum[0] + wsum[1] + wsum[2] + wsum[3];
  }
}

__global__ __launch_bounds__(256)
void aux_reduce(const float* __restrict__ p, int n, float* __restrict__ out, float scale) {
  float s = 0.f;
  for (int i = threadIdx.x; i < n; i += 256) s += p[i];
#pragma unroll
  for (int off = 32; off > 0; off >>= 1) s += __shfl_down(s, off);
  __shared__ float wsum[4];
  if ((threadIdx.x & 63) == 0) wsum[threadIdx.x >> 6] = s;
  __syncthreads();
  if (threadIdx.x == 0) out[0] = (wsum[0] + wsum[1] + wsum[2] + wsum[3]) * scale;
}

extern "C" void kernel_launch(void* const* d_in, const int* in_sizes, int n_in,
                              void* d_out, int out_size, void* d_ws, size_t ws_size,
                              hipStream_t stream) {
  const float* x    = (const float*)d_in[0];
  const float* Wih1 = (const float*)d_in[1];
  const float* Whh1 = (const float*)d_in[2];
  const float* bih1 = (const float*)d_in[3];
  const float* bhh1 = (const float*)d_in[4];
  const float* Wih2 = (const float*)d_in[5];
  const float* Whh2 = (const float*)d_in[6];
  const float* bih2 = (const float*)d_in[7];
  const float* bhh2 = (const float*)d_in[8];
  const float* Wo1  = (const float*)d_in[9];
  const float* bo1  = (const float*)d_in[10];
  const float* Wo2  = (const float*)d_in[11];
  const float* bo2  = (const float*)d_in[12];

  char* ws = (char*)d_ws;
  size_t off = 0;
  auto alloc = [&](size_t bytes) {
    char* p = ws + off;
    off = (off + bytes + 255) & ~(size_t)255;
    return p;
  };

  unsigned short* xb    = (unsigned short*)alloc((size_t)BB * TT * INF * 2);
  unsigned short* wih1b = (unsigned short*)alloc((size_t)G3 * INF * 2);
  unsigned short* whh1b = (unsigned short*)alloc((size_t)G3 * HH * 2);
  unsigned short* wih2b = (unsigned short*)alloc((size_t)G3 * HH * 2);
  unsigned short* whh2b = (unsigned short*)alloc((size_t)G3 * HH * 2);
  unsigned short* wo1b  = (unsigned short*)alloc((size_t)OUTF * HH * 2);
  unsigned short* wo2b  = (unsigned short*)alloc((size_t)OUTF * HH * 2);
  unsigned short* h1b = (unsigned short*)alloc((size_t)BB * HH * 2);
  unsigned short* h2b = (unsigned short*)alloc((size_t)BB * HH * 2);
  float* gh1  = (float*)alloc((size_t)BB * G3 * 4);   // reused as gi2 after gate1
  float* gh2  = (float*)alloc((size_t)BB * G3 * 4);
  float* o1t  = (float*)alloc((size_t)BB * OUTF * 4);
  float* auxp = (float*)alloc((size_t)TT * (BB * HH / 1024) * 4);
  float* gi2  = gh1;

  // gi1: hoist all T steps only if it (plus slack) fits the workspace
  const size_t gi1_big   = (size_t)BB * TT * G3 * 2;
  const size_t gi1_small = (size_t)BB * G3 * 2;
  const bool hoist = (off + gi1_big + (size_t)(32 << 20)) <= ws_size;
  unsigned short* gi1b = (unsigned short*)alloc(hoist ? gi1_big : gi1_small);

  float* aux = (float*)d_out + (size_t)BB * TT * OUTF;

  auto cvt = [&](const float* src, unsigned short* dst, size_t n) {
    int n4 = (int)(n / 4);
    cvt_f32_to_bf16_x4<<<dim3((n4 + 255) / 256), dim3(256), 0, stream>>>(src, dst, n4);
  };
  cvt(x,    xb,    (size_t)BB * TT * INF);
  cvt(Wih1, wih1b, (size_t)G3 * INF);
  cvt(Whh1, whh1b, (size_t)G3 * HH);
  cvt(Wih2, wih2b, (size_t)G3 * HH);
  cvt(Whh2, whh2b, (size_t)G3 * HH);
  cvt(Wo1,  wo1b,  (size_t)OUTF * HH);
  cvt(Wo2,  wo2b,  (size_t)OUTF * HH);

  hipMemsetAsync(h1b, 0, (size_t)BB * HH * 2, stream);
  hipMemsetAsync(h2b, 0, (size_t)BB * HH * 2, stream);

  const dim3 blk(256);
  const int gateGrid = BB * HH / 1024;   // 4096

  if (hoist)
    k_gi1<<<dim3(224 * 24), blk, 0, stream>>>(xb, INF, wih1b, bih1, gi1b, 224);

  for (int t = 0; t < TT; ++t) {
    if (!hoist)
      k_gi1<<<dim3(32 * 24), blk, 0, stream>>>(xb + (size_t)t * INF, (long)TT * INF,
                                               wih1b, bih1, gi1b, 32);
    k_gh_dual<<<dim3(32 * 24 * 2), blk, 0, stream>>>(h1b, h2b, whh1b, whh2b, bhh1, bhh2, gh1, gh2);
    k_gate<true><<<dim3(gateGrid), blk, 0, stream>>>(
        hoist ? gi1b + (size_t)t * G3 : gi1b, hoist ? (long)TT * G3 : (long)G3,
        gh1, h1b, nullptr);
    k_gi2_o1<<<dim3(32 * 28), blk, 0, stream>>>(h1b, wih2b, bih2, gi2, wo1b, bo1, o1t);
    k_gate<false><<<dim3(gateGrid), blk, 0, stream>>>(gi2, (long)G3, gh2, h2b,
                                                      auxp + (size_t)t * gateGrid);
    k_o2_out<<<dim3(64 * 8), blk, 0, stream>>>(h2b, wo2b, bo2, o1t,
                                               (float*)d_out + (size_t)t * OUTF);
  }
  aux_reduce<<<dim3(1), blk, 0, stream>>>(auxp, TT * gateGrid, aux,
                                          1.f / ((float)BB * (float)HH));
}

// Round 5
// 1419.319 us; speedup vs baseline: 2.3914x; 1.1051x over previous
//
#include <hip/hip_runtime.h>
#include <cstdint>

#define BB   4096
#define TT   7
#define INF  512
#define HH   1024
#define OUTF 512
#define G3   3072   // 3*H

typedef short bf16x8 __attribute__((ext_vector_type(8)));
typedef float f32x4  __attribute__((ext_vector_type(4)));

static __device__ __forceinline__ unsigned short f2bf(float f) {
  unsigned u = __float_as_uint(f);
  unsigned r = ((u >> 16) & 1u) + 0x7FFFu;   // RNE
  return (unsigned short)((u + r) >> 16);
}
static __device__ __forceinline__ float bf2f(unsigned short s) {
  return __uint_as_float(((unsigned)s) << 16);
}

#define GLDS16(gp, lp)                                                        \
  __builtin_amdgcn_global_load_lds(                                           \
      (const __attribute__((address_space(1))) void*)(gp),                    \
      (__attribute__((address_space(3))) void*)(lp), 16, 0, 0)

__device__ __forceinline__ int xcd_swz(int bid, int nwg) {
  return (bid & 7) * (nwg >> 3) + (bid >> 3);   // bijective: nwg % 8 == 0
}

__global__ __launch_bounds__(256)
void cvt_f32_to_bf16_x4(const float* __restrict__ in, unsigned short* __restrict__ out, int n4) {
  int i = blockIdx.x * 256 + threadIdx.x;
  if (i >= n4) return;
  const float4 v = ((const float4*)in)[i];
  ushort4 o;
  o.x = f2bf(v.x); o.y = f2bf(v.y); o.z = f2bf(v.z); o.w = f2bf(v.w);
  ((ushort4*)out)[i] = o;
}

// ---------------------------------------------------------------------------
// GEMM core: C[M,N] = A[M,K] @ W[N,K]^T + bias. bf16 in, f32 acc.
// BK=64, single-buffered. LDS [rows][64] with chunk-XOR swizzle:
//   LDS slot (row, cc[16B]) holds global chunk cc ^ (row&7)  (involution).
//   global_load_lds dest is LINEAR (HW constraint m104); the swizzle is applied
//   to the per-lane GLOBAL source address and to the ds_read address.
// 2 barriers per 64-wide K-step, 32 MFMA/wave between barriers.
// mode: 0 = f32 store; 1 = f32 tanh; 2 = f32 tanh + add[]; 3 = bf16 store.
// NOTE: exactly ONE gemm_core call per kernel (single 32KB __shared__).
// ---------------------------------------------------------------------------
template<int BM, int BN, int WM, int WN, int GN>
__device__ __forceinline__ void gemm_core(
    const unsigned short* __restrict__ A, long lda, long bm,
    const unsigned short* __restrict__ Wp, long ldw, int K,
    const float* __restrict__ biasp,
    void* __restrict__ Cp, long ldc,
    const float* __restrict__ addp, long ldadd, int mode)
{
  constexpr int AR = (BM * 8) / 256;   // staging rounds for A (16B chunks / 256 thr)
  constexpr int WR = (BN * 8) / 256;
  __shared__ __attribute__((aligned(16))) unsigned short sm[(BM + BN) * 64];
  unsigned short* As = sm;
  unsigned short* Ws = sm + BM * 64;
  __attribute__((address_space(3))) unsigned short* lAs =
      (__attribute__((address_space(3))) unsigned short*)As;
  __attribute__((address_space(3))) unsigned short* lWs =
      (__attribute__((address_space(3))) unsigned short*)Ws;

  const int tid  = threadIdx.x;
  const int lane = tid & 63;
  const int wid  = tid >> 6;
  const int wr = (wid / GN) * (WM * 16);
  const int wc = (wid % GN) * (WN * 16);
  const int fr = lane & 15;
  const int q2 = lane >> 4;           // 0..3: 16B k-chunk within 32-wide K-slice

  // staging: id = r*256+tid; row = id>>3, cc = id&7 (16B chunk in row);
  // LDS dest linear at id*16B; global source chunk = cc ^ (row&7).
  const unsigned short* gpa[AR];
  const unsigned short* gpw[WR];
  int lofa[AR], lofw[WR];
#pragma unroll
  for (int r = 0; r < AR; ++r) {
    const int id = r * 256 + tid;
    const int row = id >> 3, cc = id & 7;
    gpa[r] = A + (bm + row) * lda + (cc ^ (row & 7)) * 8;
    lofa[r] = id * 8;                 // elements (=16B*id)
  }
#pragma unroll
  for (int r = 0; r < WR; ++r) {
    const int id = r * 256 + tid;
    const int row = id >> 3, cc = id & 7;
    gpw[r] = Wp + (long)row * ldw + (cc ^ (row & 7)) * 8;
    lofw[r] = id * 8;
  }

  f32x4 acc[WM][WN] = {};
  for (int kt = 0; kt < K; kt += 64) {
    if (kt) __syncthreads();          // prior reads done before overwrite
#pragma unroll
    for (int r = 0; r < AR; ++r) GLDS16(gpa[r] + kt, lAs + lofa[r]);
#pragma unroll
    for (int r = 0; r < WR; ++r) GLDS16(gpw[r] + kt, lWs + lofw[r]);
    __syncthreads();                  // compiler drains vmcnt before s_barrier

#pragma unroll
    for (int ks = 0; ks < 2; ++ks) {
      bf16x8 af[WM], wf[WN];
#pragma unroll
      for (int i = 0; i < WM; ++i) {
        const int row = wr + i * 16 + fr;
        const int ch  = (ks * 4 + q2) ^ (row & 7);
        af[i] = *(const bf16x8*)&As[row * 64 + ch * 8];
      }
#pragma unroll
      for (int i = 0; i < WN; ++i) {
        const int row = wc + i * 16 + fr;
        const int ch  = (ks * 4 + q2) ^ (row & 7);
        wf[i] = *(const bf16x8*)&Ws[row * 64 + ch * 8];
      }
#pragma unroll
      for (int mi = 0; mi < WM; ++mi)
#pragma unroll
        for (int ni = 0; ni < WN; ++ni)
          acc[mi][ni] = __builtin_amdgcn_mfma_f32_16x16x32_bf16(af[mi], wf[ni], acc[mi][ni], 0, 0, 0);
    }
  }

  const int q = lane >> 4;
#pragma unroll
  for (int ni = 0; ni < WN; ++ni) {
    const int col = wc + ni * 16 + fr;
    const float bv = biasp[col];
#pragma unroll
    for (int mi = 0; mi < WM; ++mi) {
      const long row = bm + wr + mi * 16 + q * 4;
#pragma unroll
      for (int j = 0; j < 4; ++j) {
        const float v = acc[mi][ni][j] + bv;
        if (mode == 0)      ((float*)Cp)[(row + j) * ldc + col] = v;
        else if (mode == 1) ((float*)Cp)[(row + j) * ldc + col] = tanhf(v);
        else if (mode == 2) ((float*)Cp)[(row + j) * ldc + col] = tanhf(v) + addp[(row + j) * ldadd + col];
        else                ((unsigned short*)Cp)[(row + j) * ldc + col] = f2bf(v);
      }
    }
  }
}

// gi1 (bf16 out). Hoisted: A=[B*T,512], gx=224. Per-step: gx=32, lda=T*INF.
__global__ __launch_bounds__(256)
void k_gi1(const unsigned short* __restrict__ A, long lda,
           const unsigned short* __restrict__ W, const float* __restrict__ bias,
           unsigned short* __restrict__ C, int gx)
{
  const int wg = xcd_swz(blockIdx.x, gridDim.x);
  const int bx = wg % gx, by = wg / gx;
  gemm_core<128,128,4,4,2>(A, lda, (long)bx * 128, W + (long)by * 128 * INF, INF, INF,
                           bias + by * 128, C + by * 128, G3, nullptr, 0, 3);
}

// gh1 = h1 @ Whh1^T and gh2 = h2 @ Whh2^T in one 1536-block dispatch
__global__ __launch_bounds__(256)
void k_gh_dual(const unsigned short* __restrict__ h1b, const unsigned short* __restrict__ h2b,
               const unsigned short* __restrict__ W1, const unsigned short* __restrict__ W2,
               const float* __restrict__ b1, const float* __restrict__ b2,
               float* __restrict__ gh1, float* __restrict__ gh2)
{
  const int wg = xcd_swz(blockIdx.x, gridDim.x);   // 1536
  const int bx = wg % 32;
  const int by = (wg / 32) % 24;
  const int z  = wg / (32 * 24);
  const unsigned short* Aa = z ? h2b : h1b;
  const unsigned short* Ww = (z ? W2 : W1) + (long)by * 128 * HH;
  const float* bias = (z ? b2 : b1) + by * 128;
  float* C = (z ? gh2 : gh1) + by * 128;
  gemm_core<128,128,4,4,2>(Aa, HH, (long)bx * 128, Ww, HH, HH, bias, C, G3, nullptr, 0, 0);
}

// gi2 = h1 @ Wih2^T (f32) and o1t = tanh(h1 @ Wo1^T + bo1), single call site
__global__ __launch_bounds__(256)
void k_gi2_o1(const unsigned short* __restrict__ h1b,
              const unsigned short* __restrict__ Wih2, const float* __restrict__ bih2,
              float* __restrict__ gi2,
              const unsigned short* __restrict__ Wo1, const float* __restrict__ bo1,
              float* __restrict__ o1t)
{
  const int wg = xcd_swz(blockIdx.x, gridDim.x);   // 896
  const int bx = wg % 32;
  const int by = wg / 32;
  const bool g = (by < 24);
  const int bo = by - 24;
  const unsigned short* Ww = g ? (Wih2 + (long)by * 128 * HH) : (Wo1 + (long)bo * 128 * HH);
  const float* bias        = g ? (bih2 + by * 128)            : (bo1 + bo * 128);
  void* C                  = g ? (void*)(gi2 + by * 128)      : (void*)(o1t + bo * 128);
  const long ldc           = g ? (long)G3 : (long)OUTF;
  gemm_core<128,128,4,4,2>(h1b, HH, (long)bx * 128, Ww, HH, HH, bias, C, ldc,
                           nullptr, 0, g ? 0 : 1);
}

// out[b,t,:] = tanh(h2 @ Wo2^T + bo2) + o1t   (64x64 tiles, 512 blocks)
__global__ __launch_bounds__(256)
void k_o2_out(const unsigned short* __restrict__ h2b,
              const unsigned short* __restrict__ Wo2, const float* __restrict__ bo2,
              const float* __restrict__ o1t, float* __restrict__ outp)
{
  const int wg = xcd_swz(blockIdx.x, gridDim.x);   // 512
  const int bx = wg % 64;
  const int by = wg / 64;
  gemm_core<64,64,2,2,2>(h2b, HH, (long)bx * 64, Wo2 + (long)by * 64 * HH, HH, HH,
                         bo2 + by * 64, outp + by * 64, (long)TT * OUTF,
                         o1t + by * 64, OUTF, 2);
}

// GRU gate: h = (1-z)*n + z*h_old, recurrence on bf16 state hb (read+write).
template<bool GIBF>
__global__ __launch_bounds__(256)
void k_gate(const void* __restrict__ gi, long gistride,
            const float* __restrict__ gh,
            unsigned short* __restrict__ hb,
            float* __restrict__ auxp)
{
  const int i4 = blockIdx.x * 256 + threadIdx.x;
  const int e  = i4 << 2;
  const int b = e >> 10;                  // H = 1024
  const int c = e & 1023;
  f32x4 ir, iz, inn;
  if (GIBF) {
    const unsigned short* g = (const unsigned short*)gi + (long)b * gistride + c;
    const ushort4 a0 = *(const ushort4*)(g);
    const ushort4 a1 = *(const ushort4*)(g + HH);
    const ushort4 a2 = *(const ushort4*)(g + 2 * HH);
    ir  = f32x4{bf2f(a0.x), bf2f(a0.y), bf2f(a0.z), bf2f(a0.w)};
    iz  = f32x4{bf2f(a1.x), bf2f(a1.y), bf2f(a1.z), bf2f(a1.w)};
    inn = f32x4{bf2f(a2.x), bf2f(a2.y), bf2f(a2.z), bf2f(a2.w)};
  } else {
    const float* g = (const float*)gi + (long)b * gistride + c;
    ir = *(const f32x4*)g; iz = *(const f32x4*)(g + HH); inn = *(const f32x4*)(g + 2 * HH);
  }
  const float* ghp = gh + (long)b * G3 + c;
  const f32x4 hr = *(const f32x4*)ghp;
  const f32x4 hz = *(const f32x4*)(ghp + HH);
  const f32x4 hn = *(const f32x4*)(ghp + 2 * HH);
  const ushort4 ho = *(const ushort4*)(hb + e);
  const f32x4 h = f32x4{bf2f(ho.x), bf2f(ho.y), bf2f(ho.z), bf2f(ho.w)};
  f32x4 hnew;
  float vsum = 0.f;
#pragma unroll
  for (int j = 0; j < 4; ++j) {
    const float r = 1.f / (1.f + __expf(-(ir[j] + hr[j])));
    const float z = 1.f / (1.f + __expf(-(iz[j] + hz[j])));
    const float n = tanhf(inn[j] + r * hn[j]);
    hnew[j] = (1.f - z) * n + z * h[j];
    vsum += hnew[j] * hnew[j];
  }
  ushort4 o;
  o.x = f2bf(hnew[0]); o.y = f2bf(hnew[1]); o.z = f2bf(hnew[2]); o.w = f2bf(hnew[3]);
  *(ushort4*)(hb + e) = o;
  if (auxp != nullptr) {
#pragma unroll
    for (int off = 32; off > 0; off >>= 1) vsum += __shfl_down(vsum, off);
    __shared__ float wsum[4];
    if ((threadIdx.x & 63) == 0) wsum[threadIdx.x >> 6] = vsum;
    __syncthreads();
    if (threadIdx.x == 0) auxp[blockIdx.x] = wsum[0] + wsum[1] + wsum[2] + wsum[3];
  }
}

__global__ __launch_bounds__(256)
void aux_reduce(const float* __restrict__ p, int n, float* __restrict__ out, float scale) {
  float s = 0.f;
  for (int i = threadIdx.x; i < n; i += 256) s += p[i];
#pragma unroll
  for (int off = 32; off > 0; off >>= 1) s += __shfl_down(s, off);
  __shared__ float wsum[4];
  if ((threadIdx.x & 63) == 0) wsum[threadIdx.x >> 6] = s;
  __syncthreads();
  if (threadIdx.x == 0) out[0] = (wsum[0] + wsum[1] + wsum[2] + wsum[3]) * scale;
}

extern "C" void kernel_launch(void* const* d_in, const int* in_sizes, int n_in,
                              void* d_out, int out_size, void* d_ws, size_t ws_size,
                              hipStream_t stream) {
  const float* x    = (const float*)d_in[0];
  const float* Wih1 = (const float*)d_in[1];
  const float* Whh1 = (const float*)d_in[2];
  const float* bih1 = (const float*)d_in[3];
  const float* bhh1 = (const float*)d_in[4];
  const float* Wih2 = (const float*)d_in[5];
  const float* Whh2 = (const float*)d_in[6];
  const float* bih2 = (const float*)d_in[7];
  const float* bhh2 = (const float*)d_in[8];
  const float* Wo1  = (const float*)d_in[9];
  const float* bo1  = (const float*)d_in[10];
  const float* Wo2  = (const float*)d_in[11];
  const float* bo2  = (const float*)d_in[12];

  char* ws = (char*)d_ws;
  size_t off = 0;
  auto alloc = [&](size_t bytes) {
    char* p = ws + off;
    off = (off + bytes + 255) & ~(size_t)255;
    return p;
  };

  unsigned short* xb    = (unsigned short*)alloc((size_t)BB * TT * INF * 2);
  unsigned short* wih1b = (unsigned short*)alloc((size_t)G3 * INF * 2);
  unsigned short* whh1b = (unsigned short*)alloc((size_t)G3 * HH * 2);
  unsigned short* wih2b = (unsigned short*)alloc((size_t)G3 * HH * 2);
  unsigned short* whh2b = (unsigned short*)alloc((size_t)G3 * HH * 2);
  unsigned short* wo1b  = (unsigned short*)alloc((size_t)OUTF * HH * 2);
  unsigned short* wo2b  = (unsigned short*)alloc((size_t)OUTF * HH * 2);
  unsigned short* h1b = (unsigned short*)alloc((size_t)BB * HH * 2);
  unsigned short* h2b = (unsigned short*)alloc((size_t)BB * HH * 2);
  float* gh1  = (float*)alloc((size_t)BB * G3 * 4);   // reused as gi2 after gate1
  float* gh2  = (float*)alloc((size_t)BB * G3 * 4);
  float* o1t  = (float*)alloc((size_t)BB * OUTF * 4);
  float* auxp = (float*)alloc((size_t)TT * (BB * HH / 1024) * 4);
  float* gi2  = gh1;

  // gi1: hoist all T steps only if it (plus slack) fits the workspace
  const size_t gi1_big   = (size_t)BB * TT * G3 * 2;
  const size_t gi1_small = (size_t)BB * G3 * 2;
  const bool hoist = (off + gi1_big + (size_t)(32 << 20)) <= ws_size;
  unsigned short* gi1b = (unsigned short*)alloc(hoist ? gi1_big : gi1_small);

  float* aux = (float*)d_out + (size_t)BB * TT * OUTF;

  auto cvt = [&](const float* src, unsigned short* dst, size_t n) {
    int n4 = (int)(n / 4);
    cvt_f32_to_bf16_x4<<<dim3((n4 + 255) / 256), dim3(256), 0, stream>>>(src, dst, n4);
  };
  cvt(x,    xb,    (size_t)BB * TT * INF);
  cvt(Wih1, wih1b, (size_t)G3 * INF);
  cvt(Whh1, whh1b, (size_t)G3 * HH);
  cvt(Wih2, wih2b, (size_t)G3 * HH);
  cvt(Whh2, whh2b, (size_t)G3 * HH);
  cvt(Wo1,  wo1b,  (size_t)OUTF * HH);
  cvt(Wo2,  wo2b,  (size_t)OUTF * HH);

  hipMemsetAsync(h1b, 0, (size_t)BB * HH * 2, stream);
  hipMemsetAsync(h2b, 0, (size_t)BB * HH * 2, stream);

  const dim3 blk(256);
  const int gateGrid = BB * HH / 1024;   // 4096

  if (hoist)
    k_gi1<<<dim3(224 * 24), blk, 0, stream>>>(xb, INF, wih1b, bih1, gi1b, 224);

  for (int t = 0; t < TT; ++t) {
    if (!hoist)
      k_gi1<<<dim3(32 * 24), blk, 0, stream>>>(xb + (size_t)t * INF, (long)TT * INF,
                                               wih1b, bih1, gi1b, 32);
    k_gh_dual<<<dim3(32 * 24 * 2), blk, 0, stream>>>(h1b, h2b, whh1b, whh2b, bhh1, bhh2, gh1, gh2);
    k_gate<true><<<dim3(gateGrid), blk, 0, stream>>>(
        hoist ? gi1b + (size_t)t * G3 : gi1b, hoist ? (long)TT * G3 : (long)G3,
        gh1, h1b, nullptr);
    k_gi2_o1<<<dim3(32 * 28), blk, 0, stream>>>(h1b, wih2b, bih2, gi2, wo1b, bo1, o1t);
    k_gate<false><<<dim3(gateGrid), blk, 0, stream>>>(gi2, (long)G3, gh2, h2b,
                                                      auxp + (size_t)t * gateGrid);
    k_o2_out<<<dim3(64 * 8), blk, 0, stream>>>(h2b, wo2b, bo2, o1t,
                                               (float*)d_out + (size_t)t * OUTF);
  }
  aux_reduce<<<dim3(1), blk, 0, stream>>>(auxp, TT * gateGrid, aux,
                                          1.f / ((float)BB * (float)HH));
}

// Round 6
// 1416.337 us; speedup vs baseline: 2.3964x; 1.0021x over previous
//
#include <hip/hip_runtime.h>
#include <cstdint>

#define BB   4096
#define TT   7
#define INF  512
#define HH   1024
#define OUTF 512
#define G3   3072   // 3*H

typedef short bf16x8 __attribute__((ext_vector_type(8)));
typedef float f32x4  __attribute__((ext_vector_type(4)));

static __device__ __forceinline__ unsigned short f2bf(float f) {
  unsigned u = __float_as_uint(f);
  unsigned r = ((u >> 16) & 1u) + 0x7FFFu;   // RNE
  return (unsigned short)((u + r) >> 16);
}
static __device__ __forceinline__ float bf2f(unsigned short s) {
  return __uint_as_float(((unsigned)s) << 16);
}

#define GLDS16(gp, lp)                                                        \
  __builtin_amdgcn_global_load_lds(                                           \
      (const __attribute__((address_space(1))) void*)(gp),                    \
      (__attribute__((address_space(3))) void*)(lp), 16, 0, 0)

__device__ __forceinline__ int xcd_swz(int bid, int nwg) {
  return (bid & 7) * (nwg >> 3) + (bid >> 3);   // bijective: nwg % 8 == 0
}

__global__ __launch_bounds__(256)
void cvt_f32_to_bf16_x4(const float* __restrict__ in, unsigned short* __restrict__ out, int n4) {
  int i = blockIdx.x * 256 + threadIdx.x;
  if (i >= n4) return;
  const float4 v = ((const float4*)in)[i];
  ushort4 o;
  o.x = f2bf(v.x); o.y = f2bf(v.y); o.z = f2bf(v.z); o.w = f2bf(v.w);
  ((ushort4*)out)[i] = o;
}

// ---------------------------------------------------------------------------
// GEMM core: C[M,N] = A[M,K] @ W[N,K]^T + bias. bf16 in, f32 acc.
// BK=64, DOUBLE-buffered: STAGE(next K-tile) issued before ds_read+MFMA of
// current; one barrier per K-step (compiler drains vmcnt before s_barrier,
// i.e. after the 32 MFMA of useful work -> latency hidden).
// LDS [rows][64] chunk-XOR swizzle (r5-verified, conflicts==0):
//   LDS slot (row, cc[16B]) holds global chunk cc ^ (row&7); gload_lds dest
//   stays LINEAR (m104), swizzle applied to per-lane GLOBAL src + ds_read.
// mode: 0 = f32 store; 1 = f32 tanh; 2 = f32 tanh + add[]; 3 = bf16 store.
// NOTE: exactly ONE gemm_core call per kernel (single __shared__ instance).
// ---------------------------------------------------------------------------
template<int BM, int BN, int WM, int WN, int GN>
__device__ __forceinline__ void gemm_core(
    const unsigned short* __restrict__ A, long lda, long bm,
    const unsigned short* __restrict__ Wp, long ldw, int K,
    const float* __restrict__ biasp,
    void* __restrict__ Cp, long ldc,
    const float* __restrict__ addp, long ldadd, int mode)
{
  constexpr int ABUF = BM * 64;        // ushorts per A buffer
  constexpr int WBUF = BN * 64;
  constexpr int AR = (BM * 8) / 256;   // staging rounds (16B chunks / 256 thr)
  constexpr int WR = (BN * 8) / 256;
  __shared__ __attribute__((aligned(16))) unsigned short sm[2 * (ABUF + WBUF)];
  unsigned short* As = sm;
  unsigned short* Ws = sm + 2 * ABUF;
  __attribute__((address_space(3))) unsigned short* lAs =
      (__attribute__((address_space(3))) unsigned short*)As;
  __attribute__((address_space(3))) unsigned short* lWs =
      (__attribute__((address_space(3))) unsigned short*)Ws;

  const int tid  = threadIdx.x;
  const int lane = tid & 63;
  const int wid  = tid >> 6;
  const int wr = (wid / GN) * (WM * 16);
  const int wc = (wid % GN) * (WN * 16);
  const int fr = lane & 15;
  const int q2 = lane >> 4;           // 0..3: 16B k-chunk within 32-wide K-slice

  // staging: id = r*256+tid; row = id>>3, cc = id&7 (16B chunk in row);
  // LDS dest linear at id*16B; global source chunk = cc ^ (row&7).
  const unsigned short* gpa[AR];
  const unsigned short* gpw[WR];
  int lofa[AR], lofw[WR];
#pragma unroll
  for (int r = 0; r < AR; ++r) {
    const int id = r * 256 + tid;
    const int row = id >> 3, cc = id & 7;
    gpa[r] = A + (bm + row) * lda + (cc ^ (row & 7)) * 8;
    lofa[r] = id * 8;                 // elements (=16B*id)
  }
#pragma unroll
  for (int r = 0; r < WR; ++r) {
    const int id = r * 256 + tid;
    const int row = id >> 3, cc = id & 7;
    gpw[r] = Wp + (long)row * ldw + (cc ^ (row & 7)) * 8;
    lofw[r] = id * 8;
  }

#define STAGE(buf, kt) do {                                                   \
    _Pragma("unroll")                                                         \
    for (int r = 0; r < AR; ++r) GLDS16(gpa[r] + (kt), lAs + (buf) * ABUF + lofa[r]); \
    _Pragma("unroll")                                                         \
    for (int r = 0; r < WR; ++r) GLDS16(gpw[r] + (kt), lWs + (buf) * WBUF + lofw[r]); \
  } while (0)

  f32x4 acc[WM][WN] = {};
  STAGE(0, 0);
  __syncthreads();                    // drain prologue stage
  const int NK = K >> 6;
  for (int it = 0; it < NK; ++it) {
    const int cur = it & 1;
    if (it + 1 < NK) STAGE(cur ^ 1, (it + 1) << 6);   // prefetch next K-tile

#pragma unroll
    for (int ks = 0; ks < 2; ++ks) {
      bf16x8 af[WM], wf[WN];
#pragma unroll
      for (int i = 0; i < WM; ++i) {
        const int row = wr + i * 16 + fr;
        const int ch  = (ks * 4 + q2) ^ (row & 7);
        af[i] = *(const bf16x8*)&As[cur * ABUF + row * 64 + ch * 8];
      }
#pragma unroll
      for (int i = 0; i < WN; ++i) {
        const int row = wc + i * 16 + fr;
        const int ch  = (ks * 4 + q2) ^ (row & 7);
        wf[i] = *(const bf16x8*)&Ws[cur * WBUF + row * 64 + ch * 8];
      }
#pragma unroll
      for (int mi = 0; mi < WM; ++mi)
#pragma unroll
        for (int ni = 0; ni < WN; ++ni)
          acc[mi][ni] = __builtin_amdgcn_mfma_f32_16x16x32_bf16(af[mi], wf[ni], acc[mi][ni], 0, 0, 0);
    }
    __syncthreads();                  // cur reads done + prefetch drained
  }
#undef STAGE

  const int q = lane >> 4;
#pragma unroll
  for (int ni = 0; ni < WN; ++ni) {
    const int col = wc + ni * 16 + fr;
    const float bv = biasp[col];
#pragma unroll
    for (int mi = 0; mi < WM; ++mi) {
      const long row = bm + wr + mi * 16 + q * 4;
#pragma unroll
      for (int j = 0; j < 4; ++j) {
        const float v = acc[mi][ni][j] + bv;
        if (mode == 0)      ((float*)Cp)[(row + j) * ldc + col] = v;
        else if (mode == 1) ((float*)Cp)[(row + j) * ldc + col] = tanhf(v);
        else if (mode == 2) ((float*)Cp)[(row + j) * ldc + col] = tanhf(v) + addp[(row + j) * ldadd + col];
        else                ((unsigned short*)Cp)[(row + j) * ldc + col] = f2bf(v);
      }
    }
  }
}

// gi1 (bf16 out). Hoisted: A=[B*T,512], gx=224. Per-step: gx=32, lda=T*INF.
__global__ __launch_bounds__(256)
void k_gi1(const unsigned short* __restrict__ A, long lda,
           const unsigned short* __restrict__ W, const float* __restrict__ bias,
           unsigned short* __restrict__ C, int gx)
{
  const int wg = xcd_swz(blockIdx.x, gridDim.x);
  const int bx = wg % gx, by = wg / gx;
  gemm_core<128,128,4,4,2>(A, lda, (long)bx * 128, W + (long)by * 128 * INF, INF, INF,
                           bias + by * 128, C + by * 128, G3, nullptr, 0, 3);
}

// gh1 = h1 @ Whh1^T and gh2 = h2 @ Whh2^T in one 1536-block dispatch (bf16 out)
__global__ __launch_bounds__(256)
void k_gh_dual(const unsigned short* __restrict__ h1b, const unsigned short* __restrict__ h2b,
               const unsigned short* __restrict__ W1, const unsigned short* __restrict__ W2,
               const float* __restrict__ b1, const float* __restrict__ b2,
               unsigned short* __restrict__ gh1, unsigned short* __restrict__ gh2)
{
  const int wg = xcd_swz(blockIdx.x, gridDim.x);   // 1536
  const int bx = wg % 32;
  const int by = (wg / 32) % 24;
  const int z  = wg / (32 * 24);
  const unsigned short* Aa = z ? h2b : h1b;
  const unsigned short* Ww = (z ? W2 : W1) + (long)by * 128 * HH;
  const float* bias = (z ? b2 : b1) + by * 128;
  unsigned short* C = (z ? gh2 : gh1) + by * 128;
  gemm_core<128,128,4,4,2>(Aa, HH, (long)bx * 128, Ww, HH, HH, bias, C, G3, nullptr, 0, 3);
}

// gi2 = h1 @ Wih2^T (bf16) and o1t = tanh(h1 @ Wo1^T + bo1) (f32), one call site
__global__ __launch_bounds__(256)
void k_gi2_o1(const unsigned short* __restrict__ h1b,
              const unsigned short* __restrict__ Wih2, const float* __restrict__ bih2,
              unsigned short* __restrict__ gi2,
              const unsigned short* __restrict__ Wo1, const float* __restrict__ bo1,
              float* __restrict__ o1t)
{
  const int wg = xcd_swz(blockIdx.x, gridDim.x);   // 896
  const int bx = wg % 32;
  const int by = wg / 32;
  const bool g = (by < 24);
  const int bo = by - 24;
  const unsigned short* Ww = g ? (Wih2 + (long)by * 128 * HH) : (Wo1 + (long)bo * 128 * HH);
  const float* bias        = g ? (bih2 + by * 128)            : (bo1 + bo * 128);
  void* C                  = g ? (void*)(gi2 + by * 128)      : (void*)(o1t + bo * 128);
  const long ldc           = g ? (long)G3 : (long)OUTF;
  gemm_core<128,128,4,4,2>(h1b, HH, (long)bx * 128, Ww, HH, HH, bias, C, ldc,
                           nullptr, 0, g ? 3 : 1);
}

// out[b,t,:] = tanh(h2 @ Wo2^T + bo2) + o1t   (64x64 tiles, 512 blocks)
__global__ __launch_bounds__(256)
void k_o2_out(const unsigned short* __restrict__ h2b,
              const unsigned short* __restrict__ Wo2, const float* __restrict__ bo2,
              const float* __restrict__ o1t, float* __restrict__ outp)
{
  const int wg = xcd_swz(blockIdx.x, gridDim.x);   // 512
  const int bx = wg % 64;
  const int by = wg / 64;
  gemm_core<64,64,2,2,2>(h2b, HH, (long)bx * 64, Wo2 + (long)by * 64 * HH, HH, HH,
                         bo2 + by * 64, outp + by * 64, (long)TT * OUTF,
                         o1t + by * 64, OUTF, 2);
}

// GRU gate: h = (1-z)*n + z*h_old. gi, gh both bf16; recurrence on bf16 hb.
__global__ __launch_bounds__(256)
void k_gate(const unsigned short* __restrict__ gi, long gistride,
            const unsigned short* __restrict__ gh,
            unsigned short* __restrict__ hb,
            float* __restrict__ auxp)
{
  const int i4 = blockIdx.x * 256 + threadIdx.x;
  const int e  = i4 << 2;
  const int b = e >> 10;                  // H = 1024
  const int c = e & 1023;
  const unsigned short* g = gi + (long)b * gistride + c;
  const ushort4 a0 = *(const ushort4*)(g);
  const ushort4 a1 = *(const ushort4*)(g + HH);
  const ushort4 a2 = *(const ushort4*)(g + 2 * HH);
  const unsigned short* gg = gh + (long)b * G3 + c;
  const ushort4 b0 = *(const ushort4*)(gg);
  const ushort4 b1 = *(const ushort4*)(gg + HH);
  const ushort4 b2 = *(const ushort4*)(gg + 2 * HH);
  const f32x4 ir  = f32x4{bf2f(a0.x), bf2f(a0.y), bf2f(a0.z), bf2f(a0.w)};
  const f32x4 iz  = f32x4{bf2f(a1.x), bf2f(a1.y), bf2f(a1.z), bf2f(a1.w)};
  const f32x4 inn = f32x4{bf2f(a2.x), bf2f(a2.y), bf2f(a2.z), bf2f(a2.w)};
  const f32x4 hr  = f32x4{bf2f(b0.x), bf2f(b0.y), bf2f(b0.z), bf2f(b0.w)};
  const f32x4 hz  = f32x4{bf2f(b1.x), bf2f(b1.y), bf2f(b1.z), bf2f(b1.w)};
  const f32x4 hn  = f32x4{bf2f(b2.x), bf2f(b2.y), bf2f(b2.z), bf2f(b2.w)};
  const ushort4 ho = *(const ushort4*)(hb + e);
  const f32x4 h = f32x4{bf2f(ho.x), bf2f(ho.y), bf2f(ho.z), bf2f(ho.w)};
  f32x4 hnew;
  float vsum = 0.f;
#pragma unroll
  for (int j = 0; j < 4; ++j) {
    const float r = 1.f / (1.f + __expf(-(ir[j] + hr[j])));
    const float z = 1.f / (1.f + __expf(-(iz[j] + hz[j])));
    const float n = tanhf(inn[j] + r * hn[j]);
    hnew[j] = (1.f - z) * n + z * h[j];
    vsum += hnew[j] * hnew[j];
  }
  ushort4 o;
  o.x = f2bf(hnew[0]); o.y = f2bf(hnew[1]); o.z = f2bf(hnew[2]); o.w = f2bf(hnew[3]);
  *(ushort4*)(hb + e) = o;
  if (auxp != nullptr) {
#pragma unroll
    for (int off = 32; off > 0; off >>= 1) vsum += __shfl_down(vsum, off);
    __shared__ float wsum[4];
    if ((threadIdx.x & 63) == 0) wsum[threadIdx.x >> 6] = vsum;
    __syncthreads();
    if (threadIdx.x == 0) auxp[blockIdx.x] = wsum[0] + wsum[1] + wsum[2] + wsum[3];
  }
}

__global__ __launch_bounds__(256)
void aux_reduce(const float* __restrict__ p, int n, float* __restrict__ out, float scale) {
  float s = 0.f;
  for (int i = threadIdx.x; i < n; i += 256) s += p[i];
#pragma unroll
  for (int off = 32; off > 0; off >>= 1) s += __shfl_down(s, off);
  __shared__ float wsum[4];
  if ((threadIdx.x & 63) == 0) wsum[threadIdx.x >> 6] = s;
  __syncthreads();
  if (threadIdx.x == 0) out[0] = (wsum[0] + wsum[1] + wsum[2] + wsum[3]) * scale;
}

extern "C" void kernel_launch(void* const* d_in, const int* in_sizes, int n_in,
                              void* d_out, int out_size, void* d_ws, size_t ws_size,
                              hipStream_t stream) {
  const float* x    = (const float*)d_in[0];
  const float* Wih1 = (const float*)d_in[1];
  const float* Whh1 = (const float*)d_in[2];
  const float* bih1 = (const float*)d_in[3];
  const float* bhh1 = (const float*)d_in[4];
  const float* Wih2 = (const float*)d_in[5];
  const float* Whh2 = (const float*)d_in[6];
  const float* bih2 = (const float*)d_in[7];
  const float* bhh2 = (const float*)d_in[8];
  const float* Wo1  = (const float*)d_in[9];
  const float* bo1  = (const float*)d_in[10];
  const float* Wo2  = (const float*)d_in[11];
  const float* bo2  = (const float*)d_in[12];

  char* ws = (char*)d_ws;
  size_t off = 0;
  auto alloc = [&](size_t bytes) {
    char* p = ws + off;
    off = (off + bytes + 255) & ~(size_t)255;
    return p;
  };

  unsigned short* xb    = (unsigned short*)alloc((size_t)BB * TT * INF * 2);
  unsigned short* wih1b = (unsigned short*)alloc((size_t)G3 * INF * 2);
  unsigned short* whh1b = (unsigned short*)alloc((size_t)G3 * HH * 2);
  unsigned short* wih2b = (unsigned short*)alloc((size_t)G3 * HH * 2);
  unsigned short* whh2b = (unsigned short*)alloc((size_t)G3 * HH * 2);
  unsigned short* wo1b  = (unsigned short*)alloc((size_t)OUTF * HH * 2);
  unsigned short* wo2b  = (unsigned short*)alloc((size_t)OUTF * HH * 2);
  unsigned short* h1b = (unsigned short*)alloc((size_t)BB * HH * 2);
  unsigned short* h2b = (unsigned short*)alloc((size_t)BB * HH * 2);
  unsigned short* gh1 = (unsigned short*)alloc((size_t)BB * G3 * 2);  // also gi2
  unsigned short* gh2 = (unsigned short*)alloc((size_t)BB * G3 * 2);
  float* o1t  = (float*)alloc((size_t)BB * OUTF * 4);
  float* auxp = (float*)alloc((size_t)TT * (BB * HH / 1024) * 4);
  unsigned short* gi2 = gh1;          // gh1 dead after gate1; stream order safe

  // gi1: hoist all T steps only if it (plus slack) fits the workspace
  const size_t gi1_big   = (size_t)BB * TT * G3 * 2;
  const size_t gi1_small = (size_t)BB * G3 * 2;
  const bool hoist = (off + gi1_big + (size_t)(32 << 20)) <= ws_size;
  unsigned short* gi1b = (unsigned short*)alloc(hoist ? gi1_big : gi1_small);

  float* aux = (float*)d_out + (size_t)BB * TT * OUTF;

  auto cvt = [&](const float* src, unsigned short* dst, size_t n) {
    int n4 = (int)(n / 4);
    cvt_f32_to_bf16_x4<<<dim3((n4 + 255) / 256), dim3(256), 0, stream>>>(src, dst, n4);
  };
  cvt(x,    xb,    (size_t)BB * TT * INF);
  cvt(Wih1, wih1b, (size_t)G3 * INF);
  cvt(Whh1, whh1b, (size_t)G3 * HH);
  cvt(Wih2, wih2b, (size_t)G3 * HH);
  cvt(Whh2, whh2b, (size_t)G3 * HH);
  cvt(Wo1,  wo1b,  (size_t)OUTF * HH);
  cvt(Wo2,  wo2b,  (size_t)OUTF * HH);

  hipMemsetAsync(h1b, 0, (size_t)BB * HH * 2, stream);
  hipMemsetAsync(h2b, 0, (size_t)BB * HH * 2, stream);

  const dim3 blk(256);
  const int gateGrid = BB * HH / 1024;   // 4096

  if (hoist)
    k_gi1<<<dim3(224 * 24), blk, 0, stream>>>(xb, INF, wih1b, bih1, gi1b, 224);

  for (int t = 0; t < TT; ++t) {
    if (!hoist)
      k_gi1<<<dim3(32 * 24), blk, 0, stream>>>(xb + (size_t)t * INF, (long)TT * INF,
                                               wih1b, bih1, gi1b, 32);
    k_gh_dual<<<dim3(32 * 24 * 2), blk, 0, stream>>>(h1b, h2b, whh1b, whh2b, bhh1, bhh2, gh1, gh2);
    k_gate<<<dim3(gateGrid), blk, 0, stream>>>(
        hoist ? gi1b + (size_t)t * G3 : gi1b, hoist ? (long)TT * G3 : (long)G3,
        gh1, h1b, nullptr);
    k_gi2_o1<<<dim3(32 * 28), blk, 0, stream>>>(h1b, wih2b, bih2, gi2, wo1b, bo1, o1t);
    k_gate<<<dim3(gateGrid), blk, 0, stream>>>(gi2, (long)G3, gh2, h2b,
                                               auxp + (size_t)t * gateGrid);
    k_o2_out<<<dim3(64 * 8), blk, 0, stream>>>(h2b, wo2b, bo2, o1t,
                                               (float*)d_out + (size_t)t * OUTF);
  }
  aux_reduce<<<dim3(1), blk, 0, stream>>>(auxp, TT * gateGrid, aux,
                                          1.f / ((float)BB * (float)HH));
}